// Round 1
// baseline (427.643 us; speedup 1.0000x reference)
//
#include <hip/hip_runtime.h>
#include <math.h>

#define B_ 4
#define K_ 4096
#define C_ 256
#define H_ 128
#define RAD 5

// ws layout (floats):
//   s:       [B_*K_]        offset 0
//   Ssum:    [B_*C_]        offset B_*K_
//   partial: [B_*32*C_]     offset B_*K_ + B_*C_
// total ~200 KB

// ---------------- Kernel A: per-token MLP score ----------------
// s[b,k] = b2 + sum_t W2[t] * tanh(b1[t] + sum_c x[b,k,c]*W1[c,t])
// one block (128 threads) per token; thread t owns hidden unit t.
__global__ __launch_bounds__(128) void score_kernel(
    const float* __restrict__ x, const float* __restrict__ W1,
    const float* __restrict__ b1, const float* __restrict__ W2,
    const float* __restrict__ b2, float* __restrict__ s_out)
{
    __shared__ float xs[C_];
    __shared__ float red[2];
    const int tid = threadIdx.x;
    const int token = blockIdx.x;                 // b*K_ + k
    const float* xrow = x + (size_t)token * C_;
    if (tid < 64) ((float4*)xs)[tid] = ((const float4*)xrow)[tid];
    __syncthreads();

    float acc = b1[tid];
    #pragma unroll 8
    for (int c = 0; c < C_; c += 4) {
        float4 xv = *(const float4*)&xs[c];       // LDS broadcast
        acc = fmaf(xv.x, W1[(c + 0) * H_ + tid], acc);  // coalesced across tid
        acc = fmaf(xv.y, W1[(c + 1) * H_ + tid], acc);
        acc = fmaf(xv.z, W1[(c + 2) * H_ + tid], acc);
        acc = fmaf(xv.w, W1[(c + 3) * H_ + tid], acc);
    }
    float p = tanhf(acc) * W2[tid];
    #pragma unroll
    for (int off = 32; off > 0; off >>= 1) p += __shfl_down(p, off);
    if ((tid & 63) == 0) red[tid >> 6] = p;
    __syncthreads();
    if (tid == 0) s_out[token] = red[0] + red[1] + b2[0];
}

// ---------------- Kernel B1/B2: per-batch column sums ----------------
__global__ __launch_bounds__(256) void colsum_partial(
    const float* __restrict__ x, float* __restrict__ partial)
{
    const int tid = threadIdx.x;
    const int blk = blockIdx.x;                   // b*32 + chunk
    const int b = blk >> 5, chunk = blk & 31;
    const float* base = x + ((size_t)b * K_ + (size_t)chunk * 128) * C_ + tid;
    float acc = 0.f;
    for (int kk = 0; kk < 128; ++kk) acc += base[(size_t)kk * C_];
    partial[(size_t)blk * C_ + tid] = acc;
}

__global__ __launch_bounds__(256) void colsum_final(
    const float* __restrict__ partial, float* __restrict__ Ssum)
{
    const int tid = threadIdx.x;
    const int b = blockIdx.x;
    float acc = 0.f;
    #pragma unroll
    for (int chunk = 0; chunk < 32; ++chunk)
        acc += partial[(size_t)(b * 32 + chunk) * C_ + tid];
    Ssum[b * C_ + tid] = acc;
}

// ---------------- Kernel C: softmax weights row + weighted row ----------------
// one block (256 threads) per (b,i). Off-band score = 0 => weight w_off;
// band (<=11 entries) gets e^{s_j-m}/D. weighted = w_off*colsum + band corrections.
__global__ __launch_bounds__(256) void attn_kernel(
    const float* __restrict__ x, const float* __restrict__ s,
    const float* __restrict__ Ssum, float* __restrict__ out)
{
    const int tid = threadIdx.x;
    const int blk = blockIdx.x;                   // b*K_ + i
    const int b = blk >> 12;
    const int i = blk & (K_ - 1);

    __shared__ float wb[2 * RAD + 1];
    __shared__ float woff_s;
    __shared__ int j0_s, j1_s;

    if (tid == 0) {
        int j0 = i - RAD; if (j0 < 0) j0 = 0;
        int j1 = i + RAD; if (j1 > K_ - 1) j1 = K_ - 1;
        int nb = j1 - j0 + 1;
        float sv[2 * RAD + 1];
        float m = 0.f;                            // off-band scores are 0 => max >= 0
        const float* srow = s + b * K_;
        for (int jj = 0; jj < nb; ++jj) {
            float v = srow[j0 + jj];
            sv[jj] = v;
            m = fmaxf(m, v);
        }
        float e0 = expf(-m);
        float D = (float)(K_ - nb) * e0;
        for (int jj = 0; jj < nb; ++jj) { float e = expf(sv[jj] - m); sv[jj] = e; D += e; }
        float inv = 1.0f / D;
        for (int jj = 0; jj < nb; ++jj) wb[jj] = sv[jj] * inv;
        woff_s = e0 * inv;
        j0_s = j0; j1_s = j1;
    }
    __syncthreads();
    const float woff = woff_s;
    const int j0 = j0_s, j1 = j1_s;

    // ---- weights row: [K_] floats, thread tid covers [tid*16, tid*16+16) ----
    float* wrow = out + (size_t)B_ * K_ * C_ + (size_t)blk * K_;
    {
        const int jbase = tid * 16;
        const bool touches = (j1 >= jbase) && (j0 <= jbase + 15);
        if (!touches) {
            float4 v = make_float4(woff, woff, woff, woff);
            float4* p4 = (float4*)(wrow + jbase);
            p4[0] = v; p4[1] = v; p4[2] = v; p4[3] = v;
        } else {
            for (int q = 0; q < 16; ++q) {
                int j = jbase + q;
                wrow[j] = (j >= j0 && j <= j1) ? wb[j - j0] : woff;
            }
        }
    }

    // ---- weighted row: [C_] floats, thread tid owns channel tid ----
    {
        float acc = woff * Ssum[b * C_ + tid];
        const float* xb = x + ((size_t)b * K_) * C_ + tid;
        for (int j = j0; j <= j1; ++j)
            acc = fmaf(wb[j - j0] - woff, xb[(size_t)j * C_], acc);
        out[(size_t)blk * C_ + tid] = acc;
    }
}

extern "C" void kernel_launch(void* const* d_in, const int* in_sizes, int n_in,
                              void* d_out, int out_size, void* d_ws, size_t ws_size,
                              hipStream_t stream) {
    const float* x  = (const float*)d_in[0];
    const float* W1 = (const float*)d_in[1];
    const float* b1 = (const float*)d_in[2];
    const float* W2 = (const float*)d_in[3];
    const float* b2 = (const float*)d_in[4];
    float* out = (float*)d_out;

    float* ws      = (float*)d_ws;
    float* s       = ws;                          // B_*K_
    float* Ssum    = ws + B_ * K_;                // B_*C_
    float* partial = Ssum + B_ * C_;              // B_*32*C_

    score_kernel  <<<B_ * K_, 128, 0, stream>>>(x, W1, b1, W2, b2, s);
    colsum_partial<<<B_ * 32, 256, 0, stream>>>(x, partial);
    colsum_final  <<<B_,      256, 0, stream>>>(partial, Ssum);
    attn_kernel   <<<B_ * K_, 256, 0, stream>>>(x, s, Ssum, out);
}

// Round 3
// 390.853 us; speedup vs baseline: 1.0941x; 1.0941x over previous
//
#include <hip/hip_runtime.h>
#include <math.h>

#define B_ 4
#define K_ 4096
#define C_ 256
#define H_ 128
#define RAD 5

typedef float floatx4 __attribute__((ext_vector_type(4)));

// ws layout (floats): s: [B_*K_] @0, Ssum: [B_*C_] @ B_*K_   (~68 KB)
// colsum partials live in d_out's weights region (overwritten later by attn).

// ---------------- Kernel A: per-token MLP score ----------------
// 8 tokens per block of 128 threads; thread t owns hidden unit t for all 8.
// x-row loads are wave-uniform -> compiler emits s_load (SMEM pipe, free).
// W1 loads coalesced across tid, reused for all 8 tokens.
__global__ __launch_bounds__(128) void score_kernel(
    const float* __restrict__ x, const float* __restrict__ W1,
    const float* __restrict__ b1, const float* __restrict__ W2,
    const float* __restrict__ b2, float* __restrict__ s_out)
{
    const int tid = threadIdx.x;
    const int t0 = blockIdx.x * 8;
    const float* xr[8];
    #pragma unroll
    for (int t = 0; t < 8; ++t) xr[t] = x + (size_t)(t0 + t) * C_;

    float acc[8];
    float binit = b1[tid];
    #pragma unroll
    for (int t = 0; t < 8; ++t) acc[t] = binit;

    for (int c = 0; c < C_; c += 4) {
        float w0 = W1[(c + 0) * H_ + tid];
        float w1 = W1[(c + 1) * H_ + tid];
        float w2 = W1[(c + 2) * H_ + tid];
        float w3 = W1[(c + 3) * H_ + tid];
        #pragma unroll
        for (int t = 0; t < 8; ++t) {
            floatx4 xv = *(const floatx4*)&xr[t][c];   // uniform -> s_load_dwordx4
            acc[t] = fmaf(xv.x, w0, acc[t]);
            acc[t] = fmaf(xv.y, w1, acc[t]);
            acc[t] = fmaf(xv.z, w2, acc[t]);
            acc[t] = fmaf(xv.w, w3, acc[t]);
        }
    }

    __shared__ float red[2][8];
    float w2v = W2[tid];
    #pragma unroll
    for (int t = 0; t < 8; ++t) {
        float p = tanhf(acc[t]) * w2v;
        #pragma unroll
        for (int off = 32; off > 0; off >>= 1) p += __shfl_down(p, off);
        if ((tid & 63) == 0) red[tid >> 6][t] = p;
    }
    __syncthreads();
    if (tid < 8) s_out[t0 + tid] = red[0][tid] + red[1][tid] + b2[0];
}

// ---------------- Kernel B1/B2: per-batch column sums ----------------
// B1: 512 blocks, each sums 32 consecutive rows (good latency hiding).
__global__ __launch_bounds__(256) void colsum_partial(
    const float* __restrict__ x, float* __restrict__ partial)
{
    const int tid = threadIdx.x;
    const int blk = blockIdx.x;                   // rows = blk*32
    const float* base = x + (size_t)blk * 32 * C_ + tid;
    float a0 = 0.f, a1 = 0.f, a2 = 0.f, a3 = 0.f;
    #pragma unroll
    for (int kk = 0; kk < 32; kk += 4) {
        a0 += base[(size_t)(kk + 0) * C_];
        a1 += base[(size_t)(kk + 1) * C_];
        a2 += base[(size_t)(kk + 2) * C_];
        a3 += base[(size_t)(kk + 3) * C_];
    }
    partial[(size_t)blk * C_ + tid] = (a0 + a1) + (a2 + a3);
}

__global__ __launch_bounds__(256) void colsum_final(
    const float* __restrict__ partial, float* __restrict__ Ssum)
{
    const int tid = threadIdx.x;
    const int b = blockIdx.x;
    float acc = 0.f;
    for (int chunk = 0; chunk < 128; ++chunk)
        acc += partial[(size_t)(b * 128 + chunk) * C_ + tid];
    Ssum[b * C_ + tid] = acc;
}

// ---------------- Kernel C: softmax weights row + weighted row ----------------
// one block (256 threads) per (b,i). Off-band score = 0 => weight w_off;
// band (<=11 entries) gets e^{s_j-m}/D. weighted = w_off*colsum + band corrections.
// Weights stores: interleaved float4 (lane-contiguous 1KB/wave/instr), nontemporal
// so the 268MB stream doesn't evict x from L2.
__global__ __launch_bounds__(256) void attn_kernel(
    const float* __restrict__ x, const float* __restrict__ s,
    const float* __restrict__ Ssum, float* __restrict__ out)
{
    const int tid = threadIdx.x;
    const int blk = blockIdx.x;                   // b*K_ + i
    const int b = blk >> 12;
    const int i = blk & (K_ - 1);

    __shared__ float wb[2 * RAD + 1];
    __shared__ float woff_s;
    __shared__ int j0_s, j1_s;

    if (tid == 0) {
        int j0 = i - RAD; if (j0 < 0) j0 = 0;
        int j1 = i + RAD; if (j1 > K_ - 1) j1 = K_ - 1;
        int nb = j1 - j0 + 1;
        float sv[2 * RAD + 1];
        float m = 0.f;                            // off-band scores are 0 => max >= 0
        const float* srow = s + b * K_;
        for (int jj = 0; jj < nb; ++jj) {
            float v = srow[j0 + jj];
            sv[jj] = v;
            m = fmaxf(m, v);
        }
        float e0 = expf(-m);
        float D = (float)(K_ - nb) * e0;
        for (int jj = 0; jj < nb; ++jj) { float e = expf(sv[jj] - m); sv[jj] = e; D += e; }
        float inv = 1.0f / D;
        for (int jj = 0; jj < nb; ++jj) wb[jj] = sv[jj] * inv;
        woff_s = e0 * inv;
        j0_s = j0; j1_s = j1;
    }
    __syncthreads();
    const float woff = woff_s;
    const int j0 = j0_s, j1 = j1_s;

    // ---- weights row: [K_] floats = 1024 float4; thread writes f = tid + 256q ----
    floatx4* wrow4 = (floatx4*)(out + (size_t)B_ * K_ * C_ + (size_t)blk * K_);
    #pragma unroll
    for (int q = 0; q < 4; ++q) {
        const int f = tid + 256 * q;
        const int jb = f * 4;
        floatx4 v = { woff, woff, woff, woff };
        if (jb + 3 >= j0 && jb <= j1) {           // touches band (rare, <=4 threads)
            if (jb + 0 >= j0 && jb + 0 <= j1) v.x = wb[jb + 0 - j0];
            if (jb + 1 >= j0 && jb + 1 <= j1) v.y = wb[jb + 1 - j0];
            if (jb + 2 >= j0 && jb + 2 <= j1) v.z = wb[jb + 2 - j0];
            if (jb + 3 >= j0 && jb + 3 <= j1) v.w = wb[jb + 3 - j0];
        }
        __builtin_nontemporal_store(v, wrow4 + f);
    }

    // ---- weighted row: [C_] floats, thread tid owns channel tid ----
    {
        float acc = woff * Ssum[b * C_ + tid];
        const float* xb = x + ((size_t)b * K_) * C_ + tid;
        for (int j = j0; j <= j1; ++j)
            acc = fmaf(wb[j - j0] - woff, xb[(size_t)j * C_], acc);
        __builtin_nontemporal_store(acc, out + (size_t)blk * C_ + tid);
    }
}

extern "C" void kernel_launch(void* const* d_in, const int* in_sizes, int n_in,
                              void* d_out, int out_size, void* d_ws, size_t ws_size,
                              hipStream_t stream) {
    const float* x  = (const float*)d_in[0];
    const float* W1 = (const float*)d_in[1];
    const float* b1 = (const float*)d_in[2];
    const float* W2 = (const float*)d_in[3];
    const float* b2 = (const float*)d_in[4];
    float* out = (float*)d_out;

    float* ws   = (float*)d_ws;
    float* s    = ws;                             // B_*K_
    float* Ssum = ws + B_ * K_;                   // B_*C_
    // partials scratch: start of the weights region of d_out (overwritten by attn later)
    float* partial = out + (size_t)B_ * K_ * C_;  // B_*128*C_ floats = 512 KB

    score_kernel  <<<B_ * K_ / 8, 128, 0, stream>>>(x, W1, b1, W2, b2, s);
    colsum_partial<<<B_ * 128,    256, 0, stream>>>(x, partial);
    colsum_final  <<<B_,          256, 0, stream>>>(partial, Ssum);
    attn_kernel   <<<B_ * K_,     256, 0, stream>>>(x, s, Ssum, out);
}

// Round 4
// 379.820 us; speedup vs baseline: 1.1259x; 1.0290x over previous
//
#include <hip/hip_runtime.h>
#include <math.h>

#define B_ 4
#define K_ 4096
#define C_ 256
#define H_ 128
#define RAD 5
#define ROWS 8

typedef float floatx4 __attribute__((ext_vector_type(4)));

// ws layout (floats): s: [B_*K_] @0, Ssum: [B_*C_] @ B_*K_   (~68 KB)
// colsum partials live in d_out's weights region (overwritten later by attn).

// ---------------- Kernel A: per-token MLP score ----------------
// 8 tokens per block of 128 threads; thread t owns hidden unit t for all 8.
// x-row loads are wave-uniform -> scalar loads; W1 coalesced across tid.
__global__ __launch_bounds__(128) void score_kernel(
    const float* __restrict__ x, const float* __restrict__ W1,
    const float* __restrict__ b1, const float* __restrict__ W2,
    const float* __restrict__ b2, float* __restrict__ s_out)
{
    const int tid = threadIdx.x;
    const int t0 = blockIdx.x * 8;
    const float* xr[8];
    #pragma unroll
    for (int t = 0; t < 8; ++t) xr[t] = x + (size_t)(t0 + t) * C_;

    float acc[8];
    float binit = b1[tid];
    #pragma unroll
    for (int t = 0; t < 8; ++t) acc[t] = binit;

    for (int c = 0; c < C_; c += 4) {
        float w0 = W1[(c + 0) * H_ + tid];
        float w1 = W1[(c + 1) * H_ + tid];
        float w2 = W1[(c + 2) * H_ + tid];
        float w3 = W1[(c + 3) * H_ + tid];
        #pragma unroll
        for (int t = 0; t < 8; ++t) {
            floatx4 xv = *(const floatx4*)&xr[t][c];
            acc[t] = fmaf(xv.x, w0, acc[t]);
            acc[t] = fmaf(xv.y, w1, acc[t]);
            acc[t] = fmaf(xv.z, w2, acc[t]);
            acc[t] = fmaf(xv.w, w3, acc[t]);
        }
    }

    __shared__ float red[2][8];
    float w2v = W2[tid];
    #pragma unroll
    for (int t = 0; t < 8; ++t) {
        float p = tanhf(acc[t]) * w2v;
        #pragma unroll
        for (int off = 32; off > 0; off >>= 1) p += __shfl_down(p, off);
        if ((tid & 63) == 0) red[tid >> 6][t] = p;
    }
    __syncthreads();
    if (tid < 8) s_out[t0 + tid] = red[0][tid] + red[1][tid] + b2[0];
}

// ---------------- Kernel B1/B2: per-batch column sums ----------------
__global__ __launch_bounds__(256) void colsum_partial(
    const float* __restrict__ x, float* __restrict__ partial)
{
    const int tid = threadIdx.x;
    const int blk = blockIdx.x;                   // rows = blk*32
    const float* base = x + (size_t)blk * 32 * C_ + tid;
    float a0 = 0.f, a1 = 0.f, a2 = 0.f, a3 = 0.f;
    #pragma unroll
    for (int kk = 0; kk < 32; kk += 4) {
        a0 += base[(size_t)(kk + 0) * C_];
        a1 += base[(size_t)(kk + 1) * C_];
        a2 += base[(size_t)(kk + 2) * C_];
        a3 += base[(size_t)(kk + 3) * C_];
    }
    partial[(size_t)blk * C_ + tid] = (a0 + a1) + (a2 + a3);
}

__global__ __launch_bounds__(256) void colsum_final(
    const float* __restrict__ partial, float* __restrict__ Ssum)
{
    const int tid = threadIdx.x;
    const int b = blockIdx.x;
    float acc = 0.f;
    for (int chunk = 0; chunk < 128; ++chunk)
        acc += partial[(size_t)(b * 128 + chunk) * C_ + tid];
    Ssum[b * C_ + tid] = acc;
}

// ---------------- Kernel C: 8 query rows per block ----------------
// Stage s-band + x-band in LDS once; softmax scalars for the 8 rows computed
// in parallel by threads 0..7; then stream 8 weights rows (139 KB/block) and
// 8 weighted rows. Plain stores (A/B vs nt: fills hit 6.4 TB/s with plain).
__global__ __launch_bounds__(256) void attn_kernel(
    const float* __restrict__ x, const float* __restrict__ s,
    const float* __restrict__ Ssum, float* __restrict__ out)
{
    const int tid = threadIdx.x;
    const int blk = blockIdx.x;                   // b*(K_/ROWS) + tile
    const int b  = blk >> 9;                      // K_/ROWS = 512
    const int i0 = (blk & 511) * ROWS;

    const int j0t = max(0, i0 - RAD);
    const int j1t = min(K_ - 1, i0 + ROWS - 1 + RAD);
    const int ntok = j1t - j0t + 1;               // <= 18

    __shared__ float xs[ROWS + 2 * RAD][C_];      // 18 KB
    __shared__ float sb[ROWS + 2 * RAD];
    __shared__ float wb[ROWS][2 * RAD + 1];
    __shared__ float woff[ROWS];

    if (tid < ntok) sb[tid] = s[b * K_ + j0t + tid];
    const floatx4* xsrc = (const floatx4*)(x + ((size_t)b * K_ + j0t) * C_);
    floatx4* xdst = (floatx4*)&xs[0][0];
    for (int f = tid; f < ntok * (C_ / 4); f += 256) xdst[f] = xsrc[f];
    __syncthreads();

    if (tid < ROWS) {
        const int i = i0 + tid;
        const int j0 = max(0, i - RAD), j1 = min(K_ - 1, i + RAD);
        const int nb = j1 - j0 + 1;
        float m = 0.f;                            // off-band score 0 => max >= 0
        for (int j = j0; j <= j1; ++j) m = fmaxf(m, sb[j - j0t]);
        float e0 = expf(-m);
        float D = (float)(K_ - nb) * e0;
        for (int j = j0; j <= j1; ++j) {
            float e = expf(sb[j - j0t] - m);
            wb[tid][j - j0] = e;
            D += e;
        }
        float inv = 1.0f / D;
        for (int jj = 0; jj < nb; ++jj) wb[tid][jj] *= inv;
        woff[tid] = e0 * inv;
    }
    __syncthreads();

    const float sc = Ssum[b * C_ + tid];

    // ---- weights rows: 8 x 4096 floats; per row, thread writes f4 idx tid+256q ----
    #pragma unroll
    for (int r = 0; r < ROWS; ++r) {
        const int i = i0 + r;
        const int j0 = max(0, i - RAD), j1 = min(K_ - 1, i + RAD);
        const float wo = woff[r];
        floatx4* wrow4 = (floatx4*)(out + (size_t)B_ * K_ * C_ + ((size_t)b * K_ + i) * K_);
        #pragma unroll
        for (int q = 0; q < 4; ++q) {
            const int f = tid + 256 * q;
            const int jb = f * 4;
            floatx4 v = { wo, wo, wo, wo };
            if (jb + 3 >= j0 && jb <= j1) {       // touches band (<=2 threads/row/q)
                if (jb + 0 >= j0 && jb + 0 <= j1) v.x = wb[r][jb + 0 - j0];
                if (jb + 1 >= j0 && jb + 1 <= j1) v.y = wb[r][jb + 1 - j0];
                if (jb + 2 >= j0 && jb + 2 <= j1) v.z = wb[r][jb + 2 - j0];
                if (jb + 3 >= j0 && jb + 3 <= j1) v.w = wb[r][jb + 3 - j0];
            }
            wrow4[f] = v;
        }
    }

    // ---- weighted rows: 8 x 256 floats; thread owns channel tid ----
    #pragma unroll
    for (int r = 0; r < ROWS; ++r) {
        const int i = i0 + r;
        const int j0 = max(0, i - RAD), j1 = min(K_ - 1, i + RAD);
        const float wo = woff[r];
        float acc = wo * sc;
        for (int j = j0; j <= j1; ++j)
            acc = fmaf(wb[r][j - j0] - wo, xs[j - j0t][tid], acc);
        out[((size_t)b * K_ + i) * C_ + tid] = acc;
    }
}

extern "C" void kernel_launch(void* const* d_in, const int* in_sizes, int n_in,
                              void* d_out, int out_size, void* d_ws, size_t ws_size,
                              hipStream_t stream) {
    const float* x  = (const float*)d_in[0];
    const float* W1 = (const float*)d_in[1];
    const float* b1 = (const float*)d_in[2];
    const float* W2 = (const float*)d_in[3];
    const float* b2 = (const float*)d_in[4];
    float* out = (float*)d_out;

    float* ws   = (float*)d_ws;
    float* s    = ws;                             // B_*K_
    float* Ssum = ws + B_ * K_;                   // B_*C_
    float* partial = out + (size_t)B_ * K_ * C_;  // scratch in weights region

    score_kernel  <<<B_ * K_ / 8,    128, 0, stream>>>(x, W1, b1, W2, b2, s);
    colsum_partial<<<B_ * 128,       256, 0, stream>>>(x, partial);
    colsum_final  <<<B_,             256, 0, stream>>>(partial, Ssum);
    attn_kernel   <<<B_ * K_ / ROWS, 256, 0, stream>>>(x, s, Ssum, out);
}